// Round 9
// baseline (27678.586 us; speedup 1.0000x reference)
//
#include <hip/hip_runtime.h>

#define T_STEPS 65536
#define NIN 99
#define HID 64
#define G4 256   // 4*HID gates
#define TS 128   // timesteps per block in the projection kernel
#define PF 4     // z prefetch depth (steps) in the recurrence kernel

__device__ __forceinline__ float frcp(float x) { return __builtin_amdgcn_rcpf(x); }
__device__ __forceinline__ float fexp(float x) { return __expf(x); }
__device__ __forceinline__ float sigmoid_f(float x) { return frcp(1.0f + fexp(-x)); }
__device__ __forceinline__ float tanh_f(float x) {
    float ax = fabsf(x);
    float e  = fexp(2.0f * ax);                 // inf for large ax fine: rcp(inf)=0
    float r  = 1.0f - 2.0f * frcp(e + 1.0f);
    return copysignf(r, x);
}
// wave-uniform broadcast of lane `lane`'s value via readlane (VALU->SGPR)
__device__ __forceinline__ float bcast(float v, int lane) {
    return __int_as_float(__builtin_amdgcn_readlane(__float_as_int(v), lane));
}

// LDS-only barrier: waits ds ops (lgkmcnt) but leaves global loads (vmcnt)
// in flight across the barrier (R7: removed the vmcnt(0) prefetch drain).
#define BAR_LGKM() asm volatile("s_waitcnt lgkmcnt(0)\n\ts_barrier" ::: "memory")

// ---------------- Kernel 1: xz2[t][unit][4] = gates (i,f,g,o) of unit ----------------
__global__ __launch_bounds__(256, 1) void xz_kernel(
    const float* __restrict__ x, const float* __restrict__ W_ih,
    const float* __restrict__ b_ih, const float* __restrict__ b_hh,
    float* __restrict__ xz2) {
    __shared__ __align__(16) float xs[TS * 100];   // padded rows: 400 B stride
    const int g  = threadIdx.x;                    // gate row 0..255
    const int t0 = blockIdx.x * TS;
    const int unit = g & 63, d = g >> 6;           // transposed write position

    for (int i = g; i < TS * NIN; i += 256) {
        int tl = i / NIN;
        int j  = i - tl * NIN;
        xs[tl * 100 + j] = x[(size_t)t0 * NIN + i];
    }

    float w[NIN];
#pragma unroll
    for (int j = 0; j < NIN; ++j) w[j] = W_ih[g * NIN + j];
    const float bias = b_ih[g] + b_hh[g];
    __syncthreads();

    for (int tl = 0; tl < TS; ++tl) {
        const float* xr = &xs[tl * 100];
        float a0 = bias, a1 = 0.f, a2 = 0.f, a3 = 0.f;
#pragma unroll
        for (int j4 = 0; j4 < 24; ++j4) {
            float4 xv = *(const float4*)(xr + 4 * j4);
            a0 = fmaf(w[4 * j4 + 0], xv.x, a0);
            a1 = fmaf(w[4 * j4 + 1], xv.y, a1);
            a2 = fmaf(w[4 * j4 + 2], xv.z, a2);
            a3 = fmaf(w[4 * j4 + 3], xv.w, a3);
        }
        a0 = fmaf(w[96], xr[96], a0);
        a1 = fmaf(w[97], xr[97], a1);
        a2 = fmaf(w[98], xr[98], a2);
        xz2[(size_t)(t0 + tl) * G4 + unit * 4 + d] = (a0 + a1) + (a2 + a3);
    }
}

// ---------------- Kernel 2: 2-wave split-K LSTM (k=32 per wave) ----------------
// Wave wv in {0,1} owns k-chunk [32wv, 32wv+32). Lane l computes the 4 gates
// of unit l over its chunk: 32 readlane + 128 fma (8 acc chains). LDS traffic
// per step across the whole CU: 2 ds_write_b128 + 2 ds_read_b128 (R7 had 16
// pipe ops -> pipe serialization + latency dominated). Both waves form the
// identical full z sum (own regs + partner + xz), so act/update is replicated
// and h,c never leave registers. One lgkm-only barrier per step.
__global__ __launch_bounds__(128, 1) __attribute__((amdgpu_waves_per_eu(1)))
void lstm_kernel(
    const float* __restrict__ xz2, const float* __restrict__ W_hh,
    const float* __restrict__ W1, const float* __restrict__ W2,
    const float* __restrict__ b2, float* __restrict__ out) {
    __shared__ __align__(16) float4 pbuf[2][2][HID];   // [parity][wave][unit]
    __shared__ float hfin[HID];
    __shared__ float hbuf[32];
    const int tid = threadIdx.x;
    const int l   = tid & 63;
    const int wv  = tid >> 6;
    const int sb  = __builtin_amdgcn_readfirstlane(32 * wv);   // k-chunk base

    // weights: rows l(i), 64+l(f), 128+l(g), 192+l(o); cols [sb, sb+32)
    // = 8 float4 per gate, 32 float4s = 128 VGPRs. Pinned resident.
    const float* Wb = W_hh + l * HID + sb;
#define LD4(name, off) float4 name = *(const float4*)(Wb + (off))
    LD4(wi0,     0); LD4(wi1,     4); LD4(wi2,     8); LD4(wi3,    12);
    LD4(wi4,    16); LD4(wi5,    20); LD4(wi6,    24); LD4(wi7,    28);
    LD4(wf0,  4096); LD4(wf1,  4100); LD4(wf2,  4104); LD4(wf3,  4108);
    LD4(wf4,  4112); LD4(wf5,  4116); LD4(wf6,  4120); LD4(wf7,  4124);
    LD4(wg0,  8192); LD4(wg1,  8196); LD4(wg2,  8200); LD4(wg3,  8204);
    LD4(wg4,  8208); LD4(wg5,  8212); LD4(wg6,  8216); LD4(wg7,  8220);
    LD4(wo0, 12288); LD4(wo1, 12292); LD4(wo2, 12296); LD4(wo3, 12300);
    LD4(wo4, 12304); LD4(wo5, 12308); LD4(wo6, 12312); LD4(wo7, 12316);
#undef LD4

#define PIN4(v) asm volatile("" : "+v"(v.x), "+v"(v.y), "+v"(v.z), "+v"(v.w))
#define PIN_ALL()                                                   \
    PIN4(wi0); PIN4(wi1); PIN4(wi2); PIN4(wi3);                     \
    PIN4(wi4); PIN4(wi5); PIN4(wi6); PIN4(wi7);                     \
    PIN4(wf0); PIN4(wf1); PIN4(wf2); PIN4(wf3);                     \
    PIN4(wf4); PIN4(wf5); PIN4(wf6); PIN4(wf7);                     \
    PIN4(wg0); PIN4(wg1); PIN4(wg2); PIN4(wg3);                     \
    PIN4(wg4); PIN4(wg5); PIN4(wg6); PIN4(wg7);                     \
    PIN4(wo0); PIN4(wo1); PIN4(wo2); PIN4(wo3);                     \
    PIN4(wo4); PIN4(wo5); PIN4(wo6); PIN4(wo7)
    PIN_ALL();

    float h = 0.0f, c = 0.0f;       // lane l of both waves: h[l], c[l]

    // z prefetch: 4-deep double buffer, loaded by BOTH waves (identical)
    const float* zi = xz2 + 4 * l;
    float4 zcur[PF], znxt[PF];
#pragma unroll
    for (int p = 0; p < PF; ++p) zcur[p] = *(const float4*)(zi + (size_t)p * G4);

#define QUAD(KOFF, WI, WF, WG, WO, AI, AF, AG, AO)                              \
    {   float hx0 = bcast(h, sb + (KOFF) + 0);                                  \
        float hx1 = bcast(h, sb + (KOFF) + 1);                                  \
        float hx2 = bcast(h, sb + (KOFF) + 2);                                  \
        float hx3 = bcast(h, sb + (KOFF) + 3);                                  \
        AI = fmaf(WI.x, hx0, AI); AI = fmaf(WI.y, hx1, AI);                     \
        AI = fmaf(WI.z, hx2, AI); AI = fmaf(WI.w, hx3, AI);                     \
        AF = fmaf(WF.x, hx0, AF); AF = fmaf(WF.y, hx1, AF);                     \
        AF = fmaf(WF.z, hx2, AF); AF = fmaf(WF.w, hx3, AF);                     \
        AG = fmaf(WG.x, hx0, AG); AG = fmaf(WG.y, hx1, AG);                     \
        AG = fmaf(WG.z, hx2, AG); AG = fmaf(WG.w, hx3, AG);                     \
        AO = fmaf(WO.x, hx0, AO); AO = fmaf(WO.y, hx1, AO);                     \
        AO = fmaf(WO.z, hx2, AO); AO = fmaf(WO.w, hx3, AO); }

    for (int tb = 0; tb < T_STEPS; tb += PF) {
        PIN_ALL();                       // re-pin: forces arch-VGPR residency
        if (tb + PF < T_STEPS) {
#pragma unroll
            for (int p = 0; p < PF; ++p)
                znxt[p] = *(const float4*)(zi + (size_t)(tb + PF + p) * G4);
        }
#pragma unroll
        for (int u = 0; u < PF; ++u) {
            const int par = u & 1;
            // phase 1: 4 gates of unit l over this wave's 32-wide k-chunk
            float ai0 = 0.f, af0 = 0.f, ag0 = 0.f, ao0 = 0.f;
            float ai1 = 0.f, af1 = 0.f, ag1 = 0.f, ao1 = 0.f;
            QUAD( 0, wi0, wf0, wg0, wo0, ai0, af0, ag0, ao0)
            QUAD( 4, wi1, wf1, wg1, wo1, ai1, af1, ag1, ao1)
            QUAD( 8, wi2, wf2, wg2, wo2, ai0, af0, ag0, ao0)
            QUAD(12, wi3, wf3, wg3, wo3, ai1, af1, ag1, ao1)
            QUAD(16, wi4, wf4, wg4, wo4, ai0, af0, ag0, ao0)
            QUAD(20, wi5, wf5, wg5, wo5, ai1, af1, ag1, ao1)
            QUAD(24, wi6, wf6, wg6, wo6, ai0, af0, ag0, ao0)
            QUAD(28, wi7, wf7, wg7, wo7, ai1, af1, ag1, ao1)
            float ai = ai0 + ai1, af = af0 + af1, ag = ag0 + ag1, ao = ao0 + ao1;
            pbuf[par][wv][l] = make_float4(ai, af, ag, ao);
            BAR_LGKM();

            // phase 2: own partial (regs) + partner chunk (1 ds_read_b128) + z
            float4 r = pbuf[par][wv ^ 1][l];
            float4 zv = zcur[u];
            float si = (ai + r.x) + zv.x;
            float sf = (af + r.y) + zv.y;
            float sg = (ag + r.z) + zv.z;
            float so = (ao + r.w) + zv.w;
            float ig = sigmoid_f(si);
            float fg = sigmoid_f(sf);
            float gg = tanh_f(sg);
            float og = sigmoid_f(so);
            c = fmaf(fg, c, ig * gg);
            h = og * tanh_f(c);
        }
#pragma unroll
        for (int p = 0; p < PF; ++p) zcur[p] = znxt[p];
    }
#undef QUAD
#undef PIN_ALL
#undef PIN4

    // head: out = W2 @ relu(W1 @ relu(h_T)) + b2
    if (tid < HID) hfin[tid] = h;
    __syncthreads();
    if (tid < 32) {
        float s = 0.0f;
#pragma unroll
        for (int j = 0; j < HID; ++j) s += W1[tid * HID + j] * fmaxf(hfin[j], 0.0f);
        hbuf[tid] = fmaxf(s, 0.0f);
    }
    __syncthreads();
    if (tid < 3) {
        float s = b2[tid];
#pragma unroll
        for (int j = 0; j < 32; ++j) s += W2[tid * 32 + j] * hbuf[j];
        out[tid] = s;
    }
}

extern "C" void kernel_launch(void* const* d_in, const int* in_sizes, int n_in,
                              void* d_out, int out_size, void* d_ws, size_t ws_size,
                              hipStream_t stream) {
    const float* x   = (const float*)d_in[0];
    const float* Wih = (const float*)d_in[1];
    const float* Whh = (const float*)d_in[2];
    const float* bih = (const float*)d_in[3];
    const float* bhh = (const float*)d_in[4];
    const float* W1  = (const float*)d_in[5];
    const float* W2  = (const float*)d_in[6];
    const float* b2  = (const float*)d_in[7];
    float* out = (float*)d_out;
    float* xz2 = (float*)d_ws;   // T_STEPS * 256 floats = 64 MB (transposed layout)

    xz_kernel<<<T_STEPS / TS, 256, 0, stream>>>(x, Wih, bih, bhh, xz2);
    lstm_kernel<<<1, 128, 0, stream>>>(xz2, Whh, W1, W2, b2, out);
}